// Round 11
// baseline (245.301 us; speedup 1.0000x reference)
//
#include <hip/hip_runtime.h>
#include <hip/hip_bf16.h>
#include <math.h>

#define NN 2304      // H*W = 48*48
#define ROWSZ 4608   // B*N
#define SZ (ROWSZ*256)

typedef __attribute__((ext_vector_type(8))) short short8;
typedef __attribute__((ext_vector_type(4))) float f32x4;

__device__ __forceinline__ float bf2f(unsigned short u) {
    return __uint_as_float(((unsigned int)u) << 16);
}
__device__ __forceinline__ unsigned short f2bf(float f) {
    unsigned int u = __float_as_uint(f);
    u += 0x7FFFu + ((u >> 16) & 1u);   // round-to-nearest-even
    return (unsigned short)(u >> 16);
}
__device__ __forceinline__ unsigned int pack_bf2(float a, float b) {
    return (unsigned int)f2bf(a) | ((unsigned int)f2bf(b) << 16);
}

__device__ __forceinline__ float ub2f(unsigned int v, int r) {
#if defined(__has_builtin)
#if __has_builtin(__builtin_amdgcn_cvt_f32_ubyte0)
    switch (r) {
        case 0: return __builtin_amdgcn_cvt_f32_ubyte0(v);
        case 1: return __builtin_amdgcn_cvt_f32_ubyte1(v);
        case 2: return __builtin_amdgcn_cvt_f32_ubyte2(v);
        default: return __builtin_amdgcn_cvt_f32_ubyte3(v);
    }
#else
    return (float)((v >> (8*r)) & 0xFFu);
#endif
#else
    return (float)((v >> (8*r)) & 0xFFu);
#endif
}

// ---------------- fused prep: dist + scT + flag + xprep + wprep ------------
// grid 2304. Every block: dist row blk + sincos row blk.
// blocks 0..575: also x -> bf16 chunk. blocks 576..655: W transpose (m =
// (blk-576)>>4, oc0 = ((blk-576)&15)*16; m==4 only at idx 0 -> lepe wT).
// flag computed block-locally (x[0..255] exponent histogram; L2-hot).
__global__ __launch_bounds__(256) void prep_kernel(
    const void* __restrict__ x,
    const void* __restrict__ Wq, const void* __restrict__ bq,
    const void* __restrict__ Wk, const void* __restrict__ bk,
    const void* __restrict__ Wv, const void* __restrict__ bv,
    const void* __restrict__ Wo, const void* __restrict__ bo,
    const void* __restrict__ lw, const void* __restrict__ lb,
    int* __restrict__ flag, unsigned char* __restrict__ D,
    float2* __restrict__ scT, unsigned short* __restrict__ xb,
    unsigned short* __restrict__ Wt, float* __restrict__ bb,
    float* __restrict__ lwT)
{
    __shared__ float wsh[256][17];
    __shared__ int sflag;
    const int blk = blockIdx.x;
    const int t = threadIdx.x;

    // ---- dist row + sincos row (all blocks; blk = nq)
    {
        const int nq = blk;
        const int yq = (nq*21846) >> 20, xq = nq - yq*48;
        unsigned int* drow = reinterpret_cast<unsigned int*>(D + (size_t)nq*NN);
        for (int idx = t; idx < 576; idx += 256) {
            const int kp0 = idx*4;
            unsigned int wv = 0;
            #pragma unroll
            for (int r = 0; r < 4; ++r) {
                int kp = kp0 + r;
                int yk = (kp*21846) >> 20;
                int xk = kp - yk*48;
                unsigned int dist = __usad((unsigned)yq, (unsigned)yk,
                                    __usad((unsigned)xq, (unsigned)xk, 0u));
                wv |= dist << (8*r);
            }
            drow[idx] = wv;
        }
        if (t < 16) {
            const int j = t;
            const float ang = exp2f((float)j * (-0.8858474919699633f)); // 10000^(-j/15)
            float sv, cv;
            sincosf((float)nq * ang, &sv, &cv);
            scT[nq*16 + j] = make_float2(sv, cv);
        }
    }
    if (blk >= 656) return;

    // ---- block-local dtype flag
    {
        const unsigned int* xu = (const unsigned int*)x;
        if (t < 64) {
            int cnt = 0;
            for (int i = t; i < 256; i += 64) {
                unsigned int e = (xu[i] >> 7) & 0xFFu;
                cnt += (e < 87u || e > 167u) ? 1 : 0;
            }
            #pragma unroll
            for (int o = 32; o; o >>= 1) cnt += __shfl_down(cnt, o);
            if (t == 0) sflag = (cnt >= 32) ? 1 : 0;
        }
        __syncthreads();
    }
    const int F = sflag;
    if (blk == 0 && t == 0) *flag = F;

    if (blk < 576) {
        // ---- xprep chunk
        const int e = (blk*256 + t) * 8;
        if (F) {
            const float* xp = (const float*)x + e;
            float4 a0 = *reinterpret_cast<const float4*>(xp);
            float4 a1 = *reinterpret_cast<const float4*>(xp + 4);
            uint4 o;
            o.x = pack_bf2(a0.x, a0.y); o.y = pack_bf2(a0.z, a0.w);
            o.z = pack_bf2(a1.x, a1.y); o.w = pack_bf2(a1.z, a1.w);
            *reinterpret_cast<uint4*>(xb + e) = o;
        } else {
            *reinterpret_cast<uint4*>(xb + e) =
                *reinterpret_cast<const uint4*>((const unsigned short*)x + e);
        }
        return;
    }

    // ---- wprep: idx = blk-576; m = idx>>4; oc0 = (idx&15)*16
    const int idx = blk - 576;
    const int m = idx >> 4;
    if (m == 4) {
        if ((idx & 15) != 0) return;
        float wv[25];
        #pragma unroll
        for (int j = 0; j < 25; ++j)
            wv[j] = F ? ((const float*)lw)[t*25 + j]
                      : bf2f(((const unsigned short*)lw)[t*25 + j]);
        #pragma unroll
        for (int j = 0; j < 25; ++j) lwT[j*256 + t] = wv[j];
        bb[4*256 + t] = F ? ((const float*)lb)[t]
                          : bf2f(((const unsigned short*)lb)[t]);
        return;
    }
    const int oc0 = (idx & 15) * 16;
    const void* W  = (m == 0) ? Wq : (m == 1) ? Wk : (m == 2) ? Wv : Wo;
    const void* bs = (m == 0) ? bq : (m == 1) ? bk : (m == 2) ? bv : bo;
    // fold k's (32^-0.5 * log2e) into W_k and b_k
    const float scale = (m == 1) ? 0.17677669529663687f * 1.4426950408889634f : 1.0f;
    #pragma unroll
    for (int j2 = 0; j2 < 16; ++j2)
        wsh[t][j2] = F ? ((const float*)W)[t*256 + oc0 + j2]
                       : bf2f(((const unsigned short*)W)[t*256 + oc0 + j2]);
    __syncthreads();
    const int j = t >> 4, seg = t & 15;
    unsigned int u[8];
    #pragma unroll
    for (int i = 0; i < 8; ++i) {
        float v0 = wsh[seg*16 + 2*i][j]     * scale;
        float v1 = wsh[seg*16 + 2*i + 1][j] * scale;
        u[i] = pack_bf2(v0, v1);
    }
    unsigned short* drow = Wt + ((size_t)(m*256 + oc0 + j))*256 + seg*16;
    *reinterpret_cast<uint4*>(drow)     = make_uint4(u[0], u[1], u[2], u[3]);
    *reinterpret_cast<uint4*>(drow + 8) = make_uint4(u[4], u[5], u[6], u[7]);
    if ((idx & 15) == 0)
        bb[m*256 + t] = (F ? ((const float*)bs)[t]
                           : bf2f(((const unsigned short*)bs)[t])) * scale;
}

// ---------------- MFMA QKV projection + RoPE + vT --------------------------
// Single-buffered W staging (2 barriers/chunk): LDS 22.7KB -> 7 blocks/CU
// (dbuf was 43KB -> 3/CU; R4 proved dbuf neutral, R8/R9 proved occupancy wins)
__global__ __launch_bounds__(256) void qkv_mfma(
    const unsigned short* __restrict__ xb, const unsigned short* __restrict__ Wt,
    const float* __restrict__ bb, const float2* __restrict__ scT,
    unsigned short* __restrict__ q, unsigned short* __restrict__ k,
    unsigned short* __restrict__ v, unsigned short* __restrict__ vT)
{
    // LDS: Wl 20480 (256 rows * 80B) @0; sc at 20480 (16*136B);
    // out-stage (16 rows * 528B) reuses Wl after the loop.
    __shared__ __align__(16) char smem[22656];
    char* sc_lds = smem + 20480;
    const int t = threadIdx.x;
    const int w = t >> 6, lane = t & 63;
    const int q16 = lane & 15, quad = lane >> 4;
    const int m = blockIdx.y;
    const int tok0 = blockIdx.x * 16;
    const int b = (tok0 >= NN) ? 1 : 0;
    const int n0 = tok0 - b*NN;

    {
        float2 sv = scT[(size_t)(n0 + (t >> 4))*16 + (t & 15)];
        *reinterpret_cast<float2*>(sc_lds + (t >> 4)*136 + (t & 15)*8) = sv;
    }
    short8 af[8];
    #pragma unroll
    for (int kk = 0; kk < 8; ++kk)
        af[kk] = *reinterpret_cast<const short8*>(
            xb + (size_t)(tok0 + q16)*256 + kk*32 + quad*8);

    const unsigned short* Wm = Wt + (size_t)m*256*256;
    f32x4 acc[4];
    #pragma unroll
    for (int tt = 0; tt < 4; ++tt) acc[tt] = (f32x4){0.f, 0.f, 0.f, 0.f};
    for (int kk = 0; kk < 8; ++kk) {
        uint4 nw[4];
        const unsigned short* src = Wm + (size_t)t*256 + kk*32;
        #pragma unroll
        for (int s = 0; s < 4; ++s) nw[s] = *reinterpret_cast<const uint4*>(src + s*8);
        __syncthreads();             // prior chunk's Wl reads complete
        #pragma unroll
        for (int s = 0; s < 4; ++s)
            *reinterpret_cast<uint4*>(smem + t*80 + s*16) = nw[s];
        __syncthreads();
        #pragma unroll
        for (int tt = 0; tt < 4; ++tt) {
            short8 bf = *reinterpret_cast<const short8*>(
                smem + (w*64 + tt*16 + q16)*80 + quad*16);
            acc[tt] = __builtin_amdgcn_mfma_f32_16x16x32_bf16(af[kk], bf, acc[tt], 0, 0, 0);
        }
    }
    __syncthreads();                 // all Wl reads done before ostage reuse

    // epilogue: lane holds acc[tt][r] = proj[tok0+quad*4+r][oc=w*64+tt*16+q16]
    char* ostage = smem;
    float bias[4];
    #pragma unroll
    for (int tt = 0; tt < 4; ++tt) bias[tt] = bb[m*256 + w*64 + tt*16 + q16];
    if (m < 2) {
        const int odd = q16 & 1;
        #pragma unroll
        for (int tt = 0; tt < 4; ++tt) {
            const int j = ((tt & 1) << 3) + (q16 >> 1);
            #pragma unroll
            for (int r = 0; r < 4; ++r) {
                const int tokL = quad*4 + r;
                float a = acc[tt][r] + bias[tt];
                float ap = __shfl_xor(a, 1);
                float2 sc = *reinterpret_cast<const float2*>(sc_lds + tokL*136 + j*8);
                float val = odd ? fmaf(a, sc.y, ap*sc.x) : fmaf(a, sc.y, -ap*sc.x);
                *reinterpret_cast<unsigned short*>(
                    ostage + tokL*528 + (w*64 + tt*16 + q16)*2) = f2bf(val);
            }
        }
    } else {
        #pragma unroll
        for (int tt = 0; tt < 4; ++tt) {
            #pragma unroll
            for (int r = 0; r < 4; ++r)
                *reinterpret_cast<unsigned short*>(
                    ostage + (quad*4 + r)*528 + (w*64 + tt*16 + q16)*2)
                    = f2bf(acc[tt][r] + bias[tt]);
        }
    }
    __syncthreads();
    unsigned short* dst = (m == 0) ? q : (m == 1) ? k : v;
    {
        char* p = ostage + (t >> 4)*528 + (t & 15)*32;
        uint4 a0 = *reinterpret_cast<uint4*>(p);
        uint4 a1 = *reinterpret_cast<uint4*>(p + 16);
        unsigned short* drow = dst + (size_t)(tok0 + (t >> 4))*256 + (t & 15)*16;
        *reinterpret_cast<uint4*>(drow)     = a0;
        *reinterpret_cast<uint4*>(drow + 8) = a1;
    }
    if (m == 2) {
        const int h = t >> 5, d = t & 31;
        unsigned int vp[8];
        #pragma unroll
        for (int i = 0; i < 8; ++i) {
            unsigned short e0 = *reinterpret_cast<unsigned short*>(
                ostage + (2*i)*528 + (h*32 + d)*2);
            unsigned short e1 = *reinterpret_cast<unsigned short*>(
                ostage + (2*i + 1)*528 + (h*32 + d)*2);
            vp[i] = (unsigned int)e0 | ((unsigned int)e1 << 16);
        }
        unsigned short* vt = vT + ((size_t)(b*8 + h)*32 + d)*NN + n0;
        *reinterpret_cast<uint4*>(vt)     = make_uint4(vp[0], vp[1], vp[2], vp[3]);
        *reinterpret_cast<uint4*>(vt + 8) = make_uint4(vp[4], vp[5], vp[6], vp[7]);
    }
}

// ---------------- MFMA flash attention + fused lepe ------------------------
// grid (36 + 288/gz, 16, gz). blockIdx.x < 36: attn (R6-proven structure:
// cooperative dbuf LDS K/Vt, one barrier per chunk, fixed-max softmax,
// p = exp2(st + decay2*dist), dist from u8 D table; blockIdx.z takes
// 36/gz chunks -> f32 partials + l). blockIdx.x >= 36: depthwise 5x5 lepe
// (independent of attn; tiny LDS-free blocks fill scheduler gaps).
template<int DIRECT>
__global__ __launch_bounds__(256) void attn_kernel(
    const unsigned short* __restrict__ q, const unsigned short* __restrict__ k,
    const unsigned short* __restrict__ vT, const unsigned char* __restrict__ D,
    const unsigned short* __restrict__ v, const float* __restrict__ lwT,
    const float* __restrict__ bb, unsigned short* __restrict__ lepe,
    unsigned short* __restrict__ o, float* __restrict__ pacc, float* __restrict__ pl)
{
    __shared__ char smem[27648];
    const int t = threadIdx.x;
    if (blockIdx.x >= 36) {
        // ---- lepe block: pos in [0, 4608)
        const int LW = gridDim.x - 36;
        const int pos = (blockIdx.x - 36) + LW*(blockIdx.y + 16*blockIdx.z);
        const int c = t;
        const int b  = pos >= NN ? 1 : 0;
        const int yx = pos - b*NN;
        const int y  = (yx*21846) >> 20;     // yx/48 exact
        const int xx = yx - y*48;
        float acc = bb[4*256 + c];
        #pragma unroll
        for (int ky = 0; ky < 5; ++ky) {
            int yy = y + ky - 2;
            if ((unsigned)yy >= 48u) continue;
            #pragma unroll
            for (int kx = 0; kx < 5; ++kx) {
                int xc = xx + kx - 2;
                if ((unsigned)xc >= 48u) continue;
                acc = fmaf(bf2f(v[((b*NN + yy*48 + xc)<<8) + c]),
                           lwT[(ky*5 + kx)*256 + c], acc);
            }
        }
        lepe[(pos<<8) + c] = f2bf(acc);
        return;
    }
    const int w = t >> 6, lane = t & 63;
    const int q16 = lane & 15, quad = lane >> 4;
    char* PsB = smem + 19456 + w*2048;
    const int bh = blockIdx.y, b = bh >> 3, h = bh & 7;
    const int q0 = blockIdx.x*64 + w*16;
    const int nq = q0 + q16;
    const float decay2 = log2f(1.0f - exp2f(-1.0f - 0.375f*(float)h));
    short8 qfrag = *reinterpret_cast<const short8*>(q + ((size_t)(b*NN + nq))*256 + h*32 + quad*8);
    f32x4 acc0 = {0.f,0.f,0.f,0.f}, acc1 = {0.f,0.f,0.f,0.f};
    const f32x4 zero = {0.f,0.f,0.f,0.f};
    float lacc = 0.0f;
    const unsigned short* kbase = k + (size_t)(b*NN)*256 + h*32;
    const unsigned short* vtb = vT + (size_t)bh*32*NN;
    const unsigned char* Dbase = D + (size_t)nq*NN + quad*4;
    const int skr = t >> 2, skp = t & 3;
    const int svd = t >> 3, svp = t & 7;
    const int psW = q16*16 + (quad & 1)*8;
    const int qsh = quad >> 1;
    const int nchunk = 36 / gridDim.z;
    const int kt0 = blockIdx.z * nchunk;

    {
        uint4 kraw = *reinterpret_cast<const uint4*>(kbase + (kt0*64 + skr)*256 + skp*8);
        uint4 vraw = *reinterpret_cast<const uint4*>(vtb + svd*NN + kt0*64 + svp*8);
        *reinterpret_cast<uint4*>(smem + skr*80 + skp*16) = kraw;
        *reinterpret_cast<uint4*>(smem + 5120 + svd*144 + svp*16) = vraw;
    }
    __syncthreads();

    int cur = 0;
    for (int kc = 0; kc < nchunk; ++kc) {
        const int kt = kt0 + kc;
        const int ktn = (kc + 1 < nchunk) ? kt + 1 : kt;
        uint4 nk = *reinterpret_cast<const uint4*>(kbase + (ktn*64 + skr)*256 + skp*8);
        uint4 nv = *reinterpret_cast<const uint4*>(vtb + svd*NN + ktn*64 + svp*8);
        unsigned int dw[4];
        #pragma unroll
        for (int tt = 0; tt < 4; ++tt)
            dw[tt] = *reinterpret_cast<const unsigned int*>(Dbase + kt*64 + tt*16);
        char* KsB = smem + cur*9728;
        char* VtB = KsB + 5120;
        f32x4 st[4];
        #pragma unroll
        for (int tt = 0; tt < 4; ++tt) {
            short8 kf = *reinterpret_cast<const short8*>(KsB + (tt*16 + q16)*80 + quad*16);
            st[tt] = __builtin_amdgcn_mfma_f32_16x16x32_bf16(kf, qfrag, zero, 0, 0, 0);
        }
        unsigned int pk[8];
        float lsum = 0.0f;
        #pragma unroll
        for (int tt = 0; tt < 4; ++tt) {
            float p[4];
            #pragma unroll
            for (int r = 0; r < 4; ++r) {
                p[r] = exp2f(fmaf(decay2, ub2f(dw[tt], r), st[tt][r]));
                lsum += p[r];
            }
            pk[tt*2]   = __builtin_amdgcn_perm(__float_as_uint(p[1]), __float_as_uint(p[0]), 0x07060302);
            pk[tt*2+1] = __builtin_amdgcn_perm(__float_as_uint(p[3]), __float_as_uint(p[2]), 0x07060302);
        }
        lacc += lsum;
        #pragma unroll
        for (int tt = 0; tt < 4; ++tt) {
            uint2 pp; pp.x = pk[tt*2]; pp.y = pk[tt*2+1];
            *reinterpret_cast<uint2*>(PsB + (tt >> 1)*1024 + (((tt*2) + qsh) & 3)*256 + psW) = pp;
        }
        #pragma unroll
        for (int kh = 0; kh < 2; ++kh) {
            short8 pf = *reinterpret_cast<const short8*>(PsB + kh*1024 + lane*16);
            short8 v0 = *reinterpret_cast<const short8*>(VtB + q16*144 + kh*64 + quad*16);
            short8 v1 = *reinterpret_cast<const short8*>(VtB + (16 + q16)*144 + kh*64 + quad*16);
            acc0 = __builtin_amdgcn_mfma_f32_16x16x32_bf16(v0, pf, acc0, 0, 0, 0);
            acc1 = __builtin_amdgcn_mfma_f32_16x16x32_bf16(v1, pf, acc1, 0, 0, 0);
        }
        char* KsN = smem + (cur^1)*9728;
        *reinterpret_cast<uint4*>(KsN + skr*80 + skp*16) = nk;
        *reinterpret_cast<uint4*>(KsN + 5120 + svd*144 + svp*16) = nv;
        __syncthreads();
        cur ^= 1;
    }
    lacc += __shfl_xor(lacc, 16);
    lacc += __shfl_xor(lacc, 32);
    if constexpr (DIRECT) {
        float invl = 1.0f / lacc;
        unsigned short* orow = o + ((size_t)(b*NN + nq))*256 + h*32;
        uint2 w0, w1;
        w0.x = pack_bf2(acc0[0]*invl, acc0[1]*invl);
        w0.y = pack_bf2(acc0[2]*invl, acc0[3]*invl);
        w1.x = pack_bf2(acc1[0]*invl, acc1[1]*invl);
        w1.y = pack_bf2(acc1[2]*invl, acc1[3]*invl);
        *reinterpret_cast<uint2*>(orow + quad*4)      = w0;
        *reinterpret_cast<uint2*>(orow + 16 + quad*4) = w1;
    } else {
        float* pb = pacc + ((size_t)(blockIdx.z*16 + bh)*NN + nq)*32;
        *reinterpret_cast<f32x4*>(pb + quad*4)      = acc0;
        *reinterpret_cast<f32x4*>(pb + 16 + quad*4) = acc1;
        if (quad == 0) pl[((size_t)blockIdx.z*16 + bh)*NN + nq] = lacc;
    }
}

// -------- MFMA out projection: A=(norm(Σpacc)+lepe) @ Wo + bo -> out -------
// Single-buffered Wo staging: LDS 28.9KB -> 5 blocks/CU (was 49.4KB -> 3).
__global__ __launch_bounds__(256) void out_mfma(
    const unsigned short* __restrict__ o,
    const float* __restrict__ pacc, const float* __restrict__ pl,
    const unsigned short* __restrict__ lp,
    const unsigned short* __restrict__ Wt, const float* __restrict__ bb,
    const int* __restrict__ flag, void* __restrict__ out, int nsplit)
{
    // Wl 20480 @0; Astage 16*528B @20480; out-stage reuses Wl after loop.
    __shared__ __align__(16) char smem[28928];
    char* Ast = smem + 20480;
    const int t = threadIdx.x;
    const int w = t >> 6, lane = t & 63;
    const int q16 = lane & 15, quad = lane >> 4;
    const int tok0 = blockIdx.x * 16;

    // ---- A-stage: thread t -> token row t>>4, channels (t&15)*16 .. +16
    {
        const int r = t >> 4, c0 = (t & 15) * 16;
        const int nqr = tok0 + r;
        uint4 lb0 = *reinterpret_cast<const uint4*>(lp + (size_t)nqr*256 + c0);
        uint4 lb1 = *reinterpret_cast<const uint4*>(lp + (size_t)nqr*256 + c0 + 8);
        const unsigned short* lu0 = reinterpret_cast<const unsigned short*>(&lb0);
        const unsigned short* lu1 = reinterpret_cast<const unsigned short*>(&lb1);
        float av[16];
        if (nsplit == 0) {
            uint4 oa0 = *reinterpret_cast<const uint4*>(o + (size_t)nqr*256 + c0);
            uint4 oa1 = *reinterpret_cast<const uint4*>(o + (size_t)nqr*256 + c0 + 8);
            const unsigned short* ou0 = reinterpret_cast<const unsigned short*>(&oa0);
            const unsigned short* ou1 = reinterpret_cast<const unsigned short*>(&oa1);
            #pragma unroll
            for (int j = 0; j < 8; ++j) {
                av[j]     = bf2f(ou0[j]) + bf2f(lu0[j]);
                av[8 + j] = bf2f(ou1[j]) + bf2f(lu1[j]);
            }
        } else {
            const int b = nqr >= NN ? 1 : 0;
            const int nq = nqr - b*NN;
            const int bh = b*8 + (c0 >> 5);
            const int d0 = c0 & 31;          // 0 or 16
            float s[16];
            #pragma unroll
            for (int j = 0; j < 16; ++j) s[j] = 0.f;
            float lsum = 0.f;
            for (int p = 0; p < nsplit; ++p) {
                const float* pb = pacc + ((size_t)(p*16 + bh)*NN + nq)*32 + d0;
                #pragma unroll
                for (int j4 = 0; j4 < 4; ++j4) {
                    f32x4 vv = *reinterpret_cast<const f32x4*>(pb + j4*4);
                    s[j4*4+0] += vv[0]; s[j4*4+1] += vv[1];
                    s[j4*4+2] += vv[2]; s[j4*4+3] += vv[3];
                }
                lsum += pl[((size_t)p*16 + bh)*NN + nq];
            }
            float invl = 1.0f / lsum;
            #pragma unroll
            for (int j = 0; j < 8; ++j) {
                av[j]     = fmaf(s[j],     invl, bf2f(lu0[j]));
                av[8 + j] = fmaf(s[8 + j], invl, bf2f(lu1[j]));
            }
        }
        unsigned int u[8];
        #pragma unroll
        for (int i = 0; i < 8; ++i) u[i] = pack_bf2(av[2*i], av[2*i+1]);
        *reinterpret_cast<uint4*>(Ast + r*528 + c0*2)      = make_uint4(u[0],u[1],u[2],u[3]);
        *reinterpret_cast<uint4*>(Ast + r*528 + c0*2 + 16) = make_uint4(u[4],u[5],u[6],u[7]);
    }
    __syncthreads();
    // A-frags from LDS
    short8 af[8];
    #pragma unroll
    for (int kk = 0; kk < 8; ++kk)
        af[kk] = *reinterpret_cast<const short8*>(Ast + q16*528 + kk*64 + quad*16);

    const unsigned short* Wm = Wt + (size_t)3*256*256;
    f32x4 acc[4];
    #pragma unroll
    for (int tt = 0; tt < 4; ++tt) acc[tt] = (f32x4){0.f, 0.f, 0.f, 0.f};
    for (int kk = 0; kk < 8; ++kk) {
        uint4 nw[4];
        const unsigned short* src = Wm + (size_t)t*256 + kk*32;
        #pragma unroll
        for (int s2 = 0; s2 < 4; ++s2) nw[s2] = *reinterpret_cast<const uint4*>(src + s2*8);
        __syncthreads();
        #pragma unroll
        for (int s2 = 0; s2 < 4; ++s2)
            *reinterpret_cast<uint4*>(smem + t*80 + s2*16) = nw[s2];
        __syncthreads();
        #pragma unroll
        for (int tt = 0; tt < 4; ++tt) {
            short8 bf = *reinterpret_cast<const short8*>(
                smem + (w*64 + tt*16 + q16)*80 + quad*16);
            acc[tt] = __builtin_amdgcn_mfma_f32_16x16x32_bf16(af[kk], bf, acc[tt], 0, 0, 0);
        }
    }
    __syncthreads();                 // all Wl reads done before ostage reuse
    // epilogue: acc[tt][r] = out[tok0+quad*4+r][oc=w*64+tt*16+q16]
    const int F = *flag;
    float bias[4];
    #pragma unroll
    for (int tt = 0; tt < 4; ++tt) bias[tt] = bb[3*256 + w*64 + tt*16 + q16];
    if (F) {
        char* ostf = smem;               // 16 rows * 1040B f32
        #pragma unroll
        for (int tt = 0; tt < 4; ++tt) {
            #pragma unroll
            for (int r = 0; r < 4; ++r)
                *reinterpret_cast<float*>(ostf + (quad*4 + r)*1040
                    + (w*64 + tt*16 + q16)*4) = acc[tt][r] + bias[tt];
        }
        __syncthreads();
        char* p = ostf + (t >> 4)*1040 + (t & 15)*64;
        float4 x0 = *reinterpret_cast<float4*>(p);
        float4 x1 = *reinterpret_cast<float4*>(p + 16);
        float4 x2 = *reinterpret_cast<float4*>(p + 32);
        float4 x3 = *reinterpret_cast<float4*>(p + 48);
        float* drow = (float*)out + (size_t)(tok0 + (t >> 4))*256 + (t & 15)*16;
        *reinterpret_cast<float4*>(drow)      = x0;
        *reinterpret_cast<float4*>(drow + 4)  = x1;
        *reinterpret_cast<float4*>(drow + 8)  = x2;
        *reinterpret_cast<float4*>(drow + 12) = x3;
    } else {
        char* ost = smem;                // 16 rows * 528B bf16
        #pragma unroll
        for (int tt = 0; tt < 4; ++tt) {
            #pragma unroll
            for (int r = 0; r < 4; ++r)
                *reinterpret_cast<unsigned short*>(ost + (quad*4 + r)*528
                    + (w*64 + tt*16 + q16)*2) = f2bf(acc[tt][r] + bias[tt]);
        }
        __syncthreads();
        char* p = ost + (t >> 4)*528 + (t & 15)*32;
        uint4 a0 = *reinterpret_cast<uint4*>(p);
        uint4 a1 = *reinterpret_cast<uint4*>(p + 16);
        unsigned short* drow = (unsigned short*)out + (size_t)(tok0 + (t >> 4))*256 + (t & 15)*16;
        *reinterpret_cast<uint4*>(drow)     = a0;
        *reinterpret_cast<uint4*>(drow + 8) = a1;
    }
}

extern "C" void kernel_launch(void* const* d_in, const int* in_sizes, int n_in,
                              void* d_out, int out_size, void* d_ws, size_t ws_size,
                              hipStream_t stream)
{
    const void* x  = d_in[0];
    const void* Wq = d_in[1];
    const void* bq = d_in[2];
    const void* Wk = d_in[3];
    const void* bk = d_in[4];
    const void* Wv = d_in[5];
    const void* bv = d_in[6];
    const void* lw = d_in[7];
    const void* lb = d_in[8];
    const void* Wo = d_in[9];
    const void* bo = d_in[10];

    // ws: [flag 256B][q][k][v][o][lp][vT] bf16 | [D u8 5.3MB][scT 288KB]
    //     [xb bf16 2.36MB][Wt bf16 512KB][bb 5KB][lwT 25.6KB] | [pacc][pl]
    int* flag = (int*)d_ws;
    unsigned short* qb   = (unsigned short*)((char*)d_ws + 256);
    unsigned short* kbuf = qb   + (size_t)SZ;
    unsigned short* vbuf = kbuf + (size_t)SZ;
    unsigned short* obuf = vbuf + (size_t)SZ;
    unsigned short* lbuf = obuf + (size_t)SZ;
    unsigned short* vtb  = lbuf + (size_t)SZ;
    unsigned char*  Dtab = (unsigned char*)(vtb + (size_t)SZ);
    float2* scT = (float2*)(Dtab + (size_t)NN*NN);
    unsigned short* xb = (unsigned short*)(scT + (size_t)NN*16);
    unsigned short* Wt = xb + (size_t)SZ;
    float* bb  = (float*)(Wt + (size_t)4*256*256);
    float* lwT = bb + 5*256;

    const size_t base = 256 + 6*(size_t)SZ*2 + (size_t)NN*NN
                      + (size_t)NN*16*8 + (size_t)SZ*2
                      + (size_t)4*256*256*2 + (size_t)5*256*4 + (size_t)25*256*4;
    const size_t per_split = (size_t)16*NN*32*4 + (size_t)16*NN*4;  // pacc + pl
    int nsplit = 0;
    if      (ws_size >= base + 4*per_split) nsplit = 4;
    else if (ws_size >= base + 2*per_split) nsplit = 2;
    else if (ws_size >= base + 1*per_split) nsplit = 1;
    float* pacc = (float*)((char*)d_ws + base);
    float* pl   = pacc + (size_t)(nsplit ? nsplit : 1)*16*NN*32;

    prep_kernel<<<NN, 256, 0, stream>>>(x, Wq, bq, Wk, bk, Wv, bv, Wo, bo,
                                        lw, lb, flag, Dtab, scT, xb, Wt, bb, lwT);
    qkv_mfma<<<dim3(288,3), 256, 0, stream>>>(xb, Wt, bb, scT, qb, kbuf, vbuf, vtb);
    if (nsplit) {
        attn_kernel<0><<<dim3(36 + 288/nsplit, 16, nsplit), 256, 0, stream>>>(
            qb, kbuf, vtb, Dtab, vbuf, lwT, bb, lbuf, obuf, pacc, pl);
    } else {
        attn_kernel<1><<<dim3(36 + 288, 16, 1), 256, 0, stream>>>(
            qb, kbuf, vtb, Dtab, vbuf, lwT, bb, lbuf, obuf, pacc, pl);
    }
    out_mfma<<<288, 256, 0, stream>>>(obuf, pacc, pl, lbuf, Wt, bb, flag, d_out, nsplit);
}

// Round 12
// 190.617 us; speedup vs baseline: 1.2869x; 1.2869x over previous
//
#include <hip/hip_runtime.h>
#include <hip/hip_bf16.h>
#include <math.h>

#define NN 2304      // H*W = 48*48
#define ROWSZ 4608   // B*N
#define SZ (ROWSZ*256)

typedef __attribute__((ext_vector_type(8))) short short8;
typedef __attribute__((ext_vector_type(4))) float f32x4;

__device__ __forceinline__ float bf2f(unsigned short u) {
    return __uint_as_float(((unsigned int)u) << 16);
}
__device__ __forceinline__ unsigned short f2bf(float f) {
    unsigned int u = __float_as_uint(f);
    u += 0x7FFFu + ((u >> 16) & 1u);   // round-to-nearest-even
    return (unsigned short)(u >> 16);
}
__device__ __forceinline__ unsigned int pack_bf2(float a, float b) {
    return (unsigned int)f2bf(a) | ((unsigned int)f2bf(b) << 16);
}

__device__ __forceinline__ float ub2f(unsigned int v, int r) {
#if defined(__has_builtin)
#if __has_builtin(__builtin_amdgcn_cvt_f32_ubyte0)
    switch (r) {
        case 0: return __builtin_amdgcn_cvt_f32_ubyte0(v);
        case 1: return __builtin_amdgcn_cvt_f32_ubyte1(v);
        case 2: return __builtin_amdgcn_cvt_f32_ubyte2(v);
        default: return __builtin_amdgcn_cvt_f32_ubyte3(v);
    }
#else
    return (float)((v >> (8*r)) & 0xFFu);
#endif
#else
    return (float)((v >> (8*r)) & 0xFFu);
#endif
}

// ---------------- fused prep: dist + scT + flag + xprep + wprep ------------
// grid 2304. Every block: dist row blk + sincos row blk.
// blocks 0..575: also x -> bf16 chunk. blocks 576..655: W transpose (m =
// (blk-576)>>4, oc0 = ((blk-576)&15)*16; m==4 only at idx 0 -> lepe wT).
// flag computed block-locally (x[0..255] exponent histogram; L2-hot).
__global__ __launch_bounds__(256) void prep_kernel(
    const void* __restrict__ x,
    const void* __restrict__ Wq, const void* __restrict__ bq,
    const void* __restrict__ Wk, const void* __restrict__ bk,
    const void* __restrict__ Wv, const void* __restrict__ bv,
    const void* __restrict__ Wo, const void* __restrict__ bo,
    const void* __restrict__ lw, const void* __restrict__ lb,
    int* __restrict__ flag, unsigned char* __restrict__ D,
    float2* __restrict__ scT, unsigned short* __restrict__ xb,
    unsigned short* __restrict__ Wt, float* __restrict__ bb,
    float* __restrict__ lwT)
{
    __shared__ float wsh[256][17];
    __shared__ int sflag;
    const int blk = blockIdx.x;
    const int t = threadIdx.x;

    // ---- dist row + sincos row (all blocks; blk = nq)
    {
        const int nq = blk;
        const int yq = (nq*21846) >> 20, xq = nq - yq*48;
        unsigned int* drow = reinterpret_cast<unsigned int*>(D + (size_t)nq*NN);
        for (int idx = t; idx < 576; idx += 256) {
            const int kp0 = idx*4;
            unsigned int wv = 0;
            #pragma unroll
            for (int r = 0; r < 4; ++r) {
                int kp = kp0 + r;
                int yk = (kp*21846) >> 20;
                int xk = kp - yk*48;
                unsigned int dist = __usad((unsigned)yq, (unsigned)yk,
                                    __usad((unsigned)xq, (unsigned)xk, 0u));
                wv |= dist << (8*r);
            }
            drow[idx] = wv;
        }
        if (t < 16) {
            const int j = t;
            const float ang = exp2f((float)j * (-0.8858474919699633f)); // 10000^(-j/15)
            float sv, cv;
            sincosf((float)nq * ang, &sv, &cv);
            scT[nq*16 + j] = make_float2(sv, cv);
        }
    }
    if (blk >= 656) return;

    // ---- block-local dtype flag
    {
        const unsigned int* xu = (const unsigned int*)x;
        if (t < 64) {
            int cnt = 0;
            for (int i = t; i < 256; i += 64) {
                unsigned int e = (xu[i] >> 7) & 0xFFu;
                cnt += (e < 87u || e > 167u) ? 1 : 0;
            }
            #pragma unroll
            for (int o = 32; o; o >>= 1) cnt += __shfl_down(cnt, o);
            if (t == 0) sflag = (cnt >= 32) ? 1 : 0;
        }
        __syncthreads();
    }
    const int F = sflag;
    if (blk == 0 && t == 0) *flag = F;

    if (blk < 576) {
        // ---- xprep chunk
        const int e = (blk*256 + t) * 8;
        if (F) {
            const float* xp = (const float*)x + e;
            float4 a0 = *reinterpret_cast<const float4*>(xp);
            float4 a1 = *reinterpret_cast<const float4*>(xp + 4);
            uint4 o;
            o.x = pack_bf2(a0.x, a0.y); o.y = pack_bf2(a0.z, a0.w);
            o.z = pack_bf2(a1.x, a1.y); o.w = pack_bf2(a1.z, a1.w);
            *reinterpret_cast<uint4*>(xb + e) = o;
        } else {
            *reinterpret_cast<uint4*>(xb + e) =
                *reinterpret_cast<const uint4*>((const unsigned short*)x + e);
        }
        return;
    }

    // ---- wprep: idx = blk-576; m = idx>>4; oc0 = (idx&15)*16
    const int idx = blk - 576;
    const int m = idx >> 4;
    if (m == 4) {
        if ((idx & 15) != 0) return;
        float wv[25];
        #pragma unroll
        for (int j = 0; j < 25; ++j)
            wv[j] = F ? ((const float*)lw)[t*25 + j]
                      : bf2f(((const unsigned short*)lw)[t*25 + j]);
        #pragma unroll
        for (int j = 0; j < 25; ++j) lwT[j*256 + t] = wv[j];
        bb[4*256 + t] = F ? ((const float*)lb)[t]
                          : bf2f(((const unsigned short*)lb)[t]);
        return;
    }
    const int oc0 = (idx & 15) * 16;
    const void* W  = (m == 0) ? Wq : (m == 1) ? Wk : (m == 2) ? Wv : Wo;
    const void* bs = (m == 0) ? bq : (m == 1) ? bk : (m == 2) ? bv : bo;
    // fold k's (32^-0.5 * log2e) into W_k and b_k
    const float scale = (m == 1) ? 0.17677669529663687f * 1.4426950408889634f : 1.0f;
    #pragma unroll
    for (int j2 = 0; j2 < 16; ++j2)
        wsh[t][j2] = F ? ((const float*)W)[t*256 + oc0 + j2]
                       : bf2f(((const unsigned short*)W)[t*256 + oc0 + j2]);
    __syncthreads();
    const int j = t >> 4, seg = t & 15;
    unsigned int u[8];
    #pragma unroll
    for (int i = 0; i < 8; ++i) {
        float v0 = wsh[seg*16 + 2*i][j]     * scale;
        float v1 = wsh[seg*16 + 2*i + 1][j] * scale;
        u[i] = pack_bf2(v0, v1);
    }
    unsigned short* drow = Wt + ((size_t)(m*256 + oc0 + j))*256 + seg*16;
    *reinterpret_cast<uint4*>(drow)     = make_uint4(u[0], u[1], u[2], u[3]);
    *reinterpret_cast<uint4*>(drow + 8) = make_uint4(u[4], u[5], u[6], u[7]);
    if ((idx & 15) == 0)
        bb[m*256 + t] = (F ? ((const float*)bs)[t]
                           : bf2f(((const unsigned short*)bs)[t])) * scale;
}

// ---------------- MFMA QKV projection + RoPE + vT --------------------------
__global__ __launch_bounds__(256) void qkv_mfma(
    const unsigned short* __restrict__ xb, const unsigned short* __restrict__ Wt,
    const float* __restrict__ bb, const float2* __restrict__ scT,
    unsigned short* __restrict__ q, unsigned short* __restrict__ k,
    unsigned short* __restrict__ v, unsigned short* __restrict__ vT)
{
    // LDS: Wl dbuf 2*20480 (256 rows * 80B); sc at 40960 (16*136B);
    // out-stage (16 rows * 528B) reuses Wl buf0 after the loop.
    __shared__ __align__(16) char smem[43136];
    char* sc_lds = smem + 40960;
    const int t = threadIdx.x;
    const int w = t >> 6, lane = t & 63;
    const int q16 = lane & 15, quad = lane >> 4;
    const int m = blockIdx.y;
    const int tok0 = blockIdx.x * 16;
    const int b = (tok0 >= NN) ? 1 : 0;
    const int n0 = tok0 - b*NN;

    {
        float2 sv = scT[(size_t)(n0 + (t >> 4))*16 + (t & 15)];
        *reinterpret_cast<float2*>(sc_lds + (t >> 4)*136 + (t & 15)*8) = sv;
    }
    short8 af[8];
    #pragma unroll
    for (int kk = 0; kk < 8; ++kk)
        af[kk] = *reinterpret_cast<const short8*>(
            xb + (size_t)(tok0 + q16)*256 + kk*32 + quad*8);

    const unsigned short* Wm = Wt + (size_t)m*256*256;
    {
        const unsigned short* src = Wm + (size_t)t*256;
        #pragma unroll
        for (int s = 0; s < 4; ++s)
            *reinterpret_cast<uint4*>(smem + t*80 + s*16) =
                *reinterpret_cast<const uint4*>(src + s*8);
    }
    __syncthreads();

    f32x4 acc[4];
    #pragma unroll
    for (int tt = 0; tt < 4; ++tt) acc[tt] = (f32x4){0.f, 0.f, 0.f, 0.f};
    int cur = 0;
    for (int kk = 0; kk < 8; ++kk) {
        const int kkn = (kk < 7) ? kk + 1 : 7;
        uint4 nw[4];
        const unsigned short* src = Wm + (size_t)t*256 + kkn*32;
        #pragma unroll
        for (int s = 0; s < 4; ++s) nw[s] = *reinterpret_cast<const uint4*>(src + s*8);
        char* Wl = smem + cur*20480;
        #pragma unroll
        for (int tt = 0; tt < 4; ++tt) {
            short8 bf = *reinterpret_cast<const short8*>(
                Wl + (w*64 + tt*16 + q16)*80 + quad*16);
            acc[tt] = __builtin_amdgcn_mfma_f32_16x16x32_bf16(af[kk], bf, acc[tt], 0, 0, 0);
        }
        char* Wn = smem + (cur ^ 1)*20480;
        #pragma unroll
        for (int s = 0; s < 4; ++s)
            *reinterpret_cast<uint4*>(Wn + t*80 + s*16) = nw[s];
        __syncthreads();
        cur ^= 1;
    }

    // epilogue: lane holds acc[tt][r] = proj[tok0+quad*4+r][oc=w*64+tt*16+q16]
    char* ostage = smem;
    float bias[4];
    #pragma unroll
    for (int tt = 0; tt < 4; ++tt) bias[tt] = bb[m*256 + w*64 + tt*16 + q16];
    if (m < 2) {
        const int odd = q16 & 1;
        #pragma unroll
        for (int tt = 0; tt < 4; ++tt) {
            const int j = ((tt & 1) << 3) + (q16 >> 1);
            #pragma unroll
            for (int r = 0; r < 4; ++r) {
                const int tokL = quad*4 + r;
                float a = acc[tt][r] + bias[tt];
                float ap = __shfl_xor(a, 1);
                float2 sc = *reinterpret_cast<const float2*>(sc_lds + tokL*136 + j*8);
                float val = odd ? fmaf(a, sc.y, ap*sc.x) : fmaf(a, sc.y, -ap*sc.x);
                *reinterpret_cast<unsigned short*>(
                    ostage + tokL*528 + (w*64 + tt*16 + q16)*2) = f2bf(val);
            }
        }
    } else {
        #pragma unroll
        for (int tt = 0; tt < 4; ++tt) {
            #pragma unroll
            for (int r = 0; r < 4; ++r)
                *reinterpret_cast<unsigned short*>(
                    ostage + (quad*4 + r)*528 + (w*64 + tt*16 + q16)*2)
                    = f2bf(acc[tt][r] + bias[tt]);
        }
    }
    __syncthreads();
    unsigned short* dst = (m == 0) ? q : (m == 1) ? k : v;
    {
        char* p = ostage + (t >> 4)*528 + (t & 15)*32;
        uint4 a0 = *reinterpret_cast<uint4*>(p);
        uint4 a1 = *reinterpret_cast<uint4*>(p + 16);
        unsigned short* drow = dst + (size_t)(tok0 + (t >> 4))*256 + (t & 15)*16;
        *reinterpret_cast<uint4*>(drow)     = a0;
        *reinterpret_cast<uint4*>(drow + 8) = a1;
    }
    if (m == 2) {
        const int h = t >> 5, d = t & 31;
        unsigned int vp[8];
        #pragma unroll
        for (int i = 0; i < 8; ++i) {
            unsigned short e0 = *reinterpret_cast<unsigned short*>(
                ostage + (2*i)*528 + (h*32 + d)*2);
            unsigned short e1 = *reinterpret_cast<unsigned short*>(
                ostage + (2*i + 1)*528 + (h*32 + d)*2);
            vp[i] = (unsigned int)e0 | ((unsigned int)e1 << 16);
        }
        unsigned short* vt = vT + ((size_t)(b*8 + h)*32 + d)*NN + n0;
        *reinterpret_cast<uint4*>(vt)     = make_uint4(vp[0], vp[1], vp[2], vp[3]);
        *reinterpret_cast<uint4*>(vt + 8) = make_uint4(vp[4], vp[5], vp[6], vp[7]);
    }
}

// ---------------- depthwise 5x5 SAME conv on v (+ bias) --------------------
// weights pre-transposed to lwT[25][256] f32 (coalesced), bias in bb[4*256+]
__global__ __launch_bounds__(256) void lepe_kernel(const unsigned short* __restrict__ v,
    const float* __restrict__ lwT, const float* __restrict__ bb,
    unsigned short* __restrict__ lepe)
{
    int c = threadIdx.x;
    int pos = blockIdx.x;                // b*2304 + y*48 + x
    int b  = pos >= NN ? 1 : 0;
    int yx = pos - b*NN;
    int y  = (yx*21846) >> 20;           // yx/48 exact
    int xx = yx - y*48;
    float acc = bb[4*256 + c];
    #pragma unroll
    for (int ky = 0; ky < 5; ++ky) {
        int yy = y + ky - 2;
        if ((unsigned)yy >= 48u) continue;
        #pragma unroll
        for (int kx = 0; kx < 5; ++kx) {
            int xc = xx + kx - 2;
            if ((unsigned)xc >= 48u) continue;
            acc = fmaf(bf2f(v[((b*NN + yy*48 + xc)<<8) + c]),
                       lwT[(ky*5 + kx)*256 + c], acc);
        }
    }
    lepe[(pos<<8) + c] = f2bf(acc);
}

// ---------------- MFMA flash attention with decay mask ---------------------
// grid (16, 36, nsplit): blockIdx.x = bh (XCD-locality: workgroup id ≡ h
// mod 8, so each XCD's private L2 serves only 2 heads' K/Vt ≈ 590KB -> K/Vt
// fetched ~once per XCD instead of 8x replication), blockIdx.y = q-band.
// 256 thr = 4 waves; wave w: 16 q-rows; chunk = 64 kpos. R6-proven inner
// loop: cooperative dbuf LDS K/Vt staging, issue-early/write-late reg
// staging, ONE barrier per chunk. Fixed-max softmax, k pre-scaled by log2e
// -> p = exp2(st + decay2*dist), dist from u8 D table. blockIdx.z takes
// 36/nsplit chunks -> unnormalized f32 O^T partials + l.
template<int DIRECT>
__global__ __launch_bounds__(256) void attn_kernel(
    const unsigned short* __restrict__ q, const unsigned short* __restrict__ k,
    const unsigned short* __restrict__ vT, const unsigned char* __restrict__ D,
    unsigned short* __restrict__ o, float* __restrict__ pacc, float* __restrict__ pl)
{
    __shared__ char smem[27648];
    const int t = threadIdx.x;
    const int w = t >> 6, lane = t & 63;
    const int q16 = lane & 15, quad = lane >> 4;
    char* PsB = smem + 19456 + w*2048;
    const int bh = blockIdx.x, b = bh >> 3, h = bh & 7;
    const int q0 = blockIdx.y*64 + w*16;
    const int nq = q0 + q16;
    const float decay2 = log2f(1.0f - exp2f(-1.0f - 0.375f*(float)h));
    short8 qfrag = *reinterpret_cast<const short8*>(q + ((size_t)(b*NN + nq))*256 + h*32 + quad*8);
    f32x4 acc0 = {0.f,0.f,0.f,0.f}, acc1 = {0.f,0.f,0.f,0.f};
    const f32x4 zero = {0.f,0.f,0.f,0.f};
    float lacc = 0.0f;
    const unsigned short* kbase = k + (size_t)(b*NN)*256 + h*32;
    const unsigned short* vtb = vT + (size_t)bh*32*NN;
    const unsigned char* Dbase = D + (size_t)nq*NN + quad*4;
    const int skr = t >> 2, skp = t & 3;
    const int svd = t >> 3, svp = t & 7;
    const int psW = q16*16 + (quad & 1)*8;
    const int qsh = quad >> 1;
    const int nchunk = 36 / gridDim.z;
    const int kt0 = blockIdx.z * nchunk;

    {
        uint4 kraw = *reinterpret_cast<const uint4*>(kbase + (kt0*64 + skr)*256 + skp*8);
        uint4 vraw = *reinterpret_cast<const uint4*>(vtb + svd*NN + kt0*64 + svp*8);
        *reinterpret_cast<uint4*>(smem + skr*80 + skp*16) = kraw;
        *reinterpret_cast<uint4*>(smem + 5120 + svd*144 + svp*16) = vraw;
    }
    __syncthreads();

    int cur = 0;
    for (int kc = 0; kc < nchunk; ++kc) {
        const int kt = kt0 + kc;
        const int ktn = (kc + 1 < nchunk) ? kt + 1 : kt;
        uint4 nk = *reinterpret_cast<const uint4*>(kbase + (ktn*64 + skr)*256 + skp*8);
        uint4 nv = *reinterpret_cast<const uint4*>(vtb + svd*NN + ktn*64 + svp*8);
        unsigned int dw[4];
        #pragma unroll
        for (int tt = 0; tt < 4; ++tt)
            dw[tt] = *reinterpret_cast<const unsigned int*>(Dbase + kt*64 + tt*16);
        char* KsB = smem + cur*9728;
        char* VtB = KsB + 5120;
        f32x4 st[4];
        #pragma unroll
        for (int tt = 0; tt < 4; ++tt) {
            short8 kf = *reinterpret_cast<const short8*>(KsB + (tt*16 + q16)*80 + quad*16);
            st[tt] = __builtin_amdgcn_mfma_f32_16x16x32_bf16(kf, qfrag, zero, 0, 0, 0);
        }
        unsigned int pk[8];
        float lsum = 0.0f;
        #pragma unroll
        for (int tt = 0; tt < 4; ++tt) {
            float p[4];
            #pragma unroll
            for (int r = 0; r < 4; ++r) {
                p[r] = exp2f(fmaf(decay2, ub2f(dw[tt], r), st[tt][r]));
                lsum += p[r];
            }
            pk[tt*2]   = __builtin_amdgcn_perm(__float_as_uint(p[1]), __float_as_uint(p[0]), 0x07060302);
            pk[tt*2+1] = __builtin_amdgcn_perm(__float_as_uint(p[3]), __float_as_uint(p[2]), 0x07060302);
        }
        lacc += lsum;
        #pragma unroll
        for (int tt = 0; tt < 4; ++tt) {
            uint2 pp; pp.x = pk[tt*2]; pp.y = pk[tt*2+1];
            *reinterpret_cast<uint2*>(PsB + (tt >> 1)*1024 + (((tt*2) + qsh) & 3)*256 + psW) = pp;
        }
        #pragma unroll
        for (int kh = 0; kh < 2; ++kh) {
            short8 pf = *reinterpret_cast<const short8*>(PsB + kh*1024 + lane*16);
            short8 v0 = *reinterpret_cast<const short8*>(VtB + q16*144 + kh*64 + quad*16);
            short8 v1 = *reinterpret_cast<const short8*>(VtB + (16 + q16)*144 + kh*64 + quad*16);
            acc0 = __builtin_amdgcn_mfma_f32_16x16x32_bf16(v0, pf, acc0, 0, 0, 0);
            acc1 = __builtin_amdgcn_mfma_f32_16x16x32_bf16(v1, pf, acc1, 0, 0, 0);
        }
        char* KsN = smem + (cur^1)*9728;
        *reinterpret_cast<uint4*>(KsN + skr*80 + skp*16) = nk;
        *reinterpret_cast<uint4*>(KsN + 5120 + svd*144 + svp*16) = nv;
        __syncthreads();
        cur ^= 1;
    }
    lacc += __shfl_xor(lacc, 16);
    lacc += __shfl_xor(lacc, 32);
    if constexpr (DIRECT) {
        float invl = 1.0f / lacc;
        unsigned short* orow = o + ((size_t)(b*NN + nq))*256 + h*32;
        uint2 w0, w1;
        w0.x = pack_bf2(acc0[0]*invl, acc0[1]*invl);
        w0.y = pack_bf2(acc0[2]*invl, acc0[3]*invl);
        w1.x = pack_bf2(acc1[0]*invl, acc1[1]*invl);
        w1.y = pack_bf2(acc1[2]*invl, acc1[3]*invl);
        *reinterpret_cast<uint2*>(orow + quad*4)      = w0;
        *reinterpret_cast<uint2*>(orow + 16 + quad*4) = w1;
    } else {
        float* pb = pacc + ((size_t)(blockIdx.z*16 + bh)*NN + nq)*32;
        *reinterpret_cast<f32x4*>(pb + quad*4)      = acc0;
        *reinterpret_cast<f32x4*>(pb + 16 + quad*4) = acc1;
        if (quad == 0) pl[((size_t)blockIdx.z*16 + bh)*NN + nq] = lacc;
    }
}

// -------- MFMA out projection: A=(norm(Σpacc)+lepe) @ Wo + bo -> out -------
__global__ __launch_bounds__(256) void out_mfma(
    const unsigned short* __restrict__ o,
    const float* __restrict__ pacc, const float* __restrict__ pl,
    const unsigned short* __restrict__ lp,
    const unsigned short* __restrict__ Wt, const float* __restrict__ bb,
    const int* __restrict__ flag, void* __restrict__ out, int nsplit)
{
    // Wl dbuf 2*20480 @0; Astage 16*528B @40960; out-stage reuses Wl buf0.
    __shared__ __align__(16) char smem[49408];
    char* Ast = smem + 40960;
    const int t = threadIdx.x;
    const int w = t >> 6, lane = t & 63;
    const int q16 = lane & 15, quad = lane >> 4;
    const int tok0 = blockIdx.x * 16;

    // ---- A-stage: thread t -> token row t>>4, channels (t&15)*16 .. +16
    {
        const int r = t >> 4, c0 = (t & 15) * 16;
        const int nqr = tok0 + r;
        uint4 lb0 = *reinterpret_cast<const uint4*>(lp + (size_t)nqr*256 + c0);
        uint4 lb1 = *reinterpret_cast<const uint4*>(lp + (size_t)nqr*256 + c0 + 8);
        const unsigned short* lu0 = reinterpret_cast<const unsigned short*>(&lb0);
        const unsigned short* lu1 = reinterpret_cast<const unsigned short*>(&lb1);
        float av[16];
        if (nsplit == 0) {
            uint4 oa0 = *reinterpret_cast<const uint4*>(o + (size_t)nqr*256 + c0);
            uint4 oa1 = *reinterpret_cast<const uint4*>(o + (size_t)nqr*256 + c0 + 8);
            const unsigned short* ou0 = reinterpret_cast<const unsigned short*>(&oa0);
            const unsigned short* ou1 = reinterpret_cast<const unsigned short*>(&oa1);
            #pragma unroll
            for (int j = 0; j < 8; ++j) {
                av[j]     = bf2f(ou0[j]) + bf2f(lu0[j]);
                av[8 + j] = bf2f(ou1[j]) + bf2f(lu1[j]);
            }
        } else {
            const int b = nqr >= NN ? 1 : 0;
            const int nq = nqr - b*NN;
            const int bh = b*8 + (c0 >> 5);
            const int d0 = c0 & 31;          // 0 or 16
            float s[16];
            #pragma unroll
            for (int j = 0; j < 16; ++j) s[j] = 0.f;
            float lsum = 0.f;
            for (int p = 0; p < nsplit; ++p) {
                const float* pb = pacc + ((size_t)(p*16 + bh)*NN + nq)*32 + d0;
                #pragma unroll
                for (int j4 = 0; j4 < 4; ++j4) {
                    f32x4 vv = *reinterpret_cast<const f32x4*>(pb + j4*4);
                    s[j4*4+0] += vv[0]; s[j4*4+1] += vv[1];
                    s[j4*4+2] += vv[2]; s[j4*4+3] += vv[3];
                }
                lsum += pl[((size_t)p*16 + bh)*NN + nq];
            }
            float invl = 1.0f / lsum;
            #pragma unroll
            for (int j = 0; j < 8; ++j) {
                av[j]     = fmaf(s[j],     invl, bf2f(lu0[j]));
                av[8 + j] = fmaf(s[8 + j], invl, bf2f(lu1[j]));
            }
        }
        unsigned int u[8];
        #pragma unroll
        for (int i = 0; i < 8; ++i) u[i] = pack_bf2(av[2*i], av[2*i+1]);
        *reinterpret_cast<uint4*>(Ast + r*528 + c0*2)      = make_uint4(u[0],u[1],u[2],u[3]);
        *reinterpret_cast<uint4*>(Ast + r*528 + c0*2 + 16) = make_uint4(u[4],u[5],u[6],u[7]);
    }
    // ---- stage Wo chunk 0 into buf0
    const unsigned short* Wm = Wt + (size_t)3*256*256;
    {
        const unsigned short* src = Wm + (size_t)t*256;
        #pragma unroll
        for (int s2 = 0; s2 < 4; ++s2)
            *reinterpret_cast<uint4*>(smem + t*80 + s2*16) =
                *reinterpret_cast<const uint4*>(src + s2*8);
    }
    __syncthreads();
    // A-frags from LDS
    short8 af[8];
    #pragma unroll
    for (int kk = 0; kk < 8; ++kk)
        af[kk] = *reinterpret_cast<const short8*>(Ast + q16*528 + kk*64 + quad*16);

    f32x4 acc[4];
    #pragma unroll
    for (int tt = 0; tt < 4; ++tt) acc[tt] = (f32x4){0.f, 0.f, 0.f, 0.f};
    int cur = 0;
    for (int kk = 0; kk < 8; ++kk) {
        const int kkn = (kk < 7) ? kk + 1 : 7;
        uint4 nw[4];
        const unsigned short* src = Wm + (size_t)t*256 + kkn*32;
        #pragma unroll
        for (int s2 = 0; s2 < 4; ++s2) nw[s2] = *reinterpret_cast<const uint4*>(src + s2*8);
        char* Wl = smem + cur*20480;
        #pragma unroll
        for (int tt = 0; tt < 4; ++tt) {
            short8 bf = *reinterpret_cast<const short8*>(
                Wl + (w*64 + tt*16 + q16)*80 + quad*16);
            acc[tt] = __builtin_amdgcn_mfma_f32_16x16x32_bf16(af[kk], bf, acc[tt], 0, 0, 0);
        }
        char* Wn = smem + (cur ^ 1)*20480;
        #pragma unroll
        for (int s2 = 0; s2 < 4; ++s2)
            *reinterpret_cast<uint4*>(Wn + t*80 + s2*16) = nw[s2];
        __syncthreads();
        cur ^= 1;
    }
    // epilogue: acc[tt][r] = out[tok0+quad*4+r][oc=w*64+tt*16+q16]
    const int F = *flag;
    float bias[4];
    #pragma unroll
    for (int tt = 0; tt < 4; ++tt) bias[tt] = bb[3*256 + w*64 + tt*16 + q16];
    if (F) {
        char* ostf = smem;               // 16 rows * 1040B f32
        #pragma unroll
        for (int tt = 0; tt < 4; ++tt) {
            #pragma unroll
            for (int r = 0; r < 4; ++r)
                *reinterpret_cast<float*>(ostf + (quad*4 + r)*1040
                    + (w*64 + tt*16 + q16)*4) = acc[tt][r] + bias[tt];
        }
        __syncthreads();
        char* p = ostf + (t >> 4)*1040 + (t & 15)*64;
        float4 x0 = *reinterpret_cast<float4*>(p);
        float4 x1 = *reinterpret_cast<float4*>(p + 16);
        float4 x2 = *reinterpret_cast<float4*>(p + 32);
        float4 x3 = *reinterpret_cast<float4*>(p + 48);
        float* drow = (float*)out + (size_t)(tok0 + (t >> 4))*256 + (t & 15)*16;
        *reinterpret_cast<float4*>(drow)      = x0;
        *reinterpret_cast<float4*>(drow + 4)  = x1;
        *reinterpret_cast<float4*>(drow + 8)  = x2;
        *reinterpret_cast<float4*>(drow + 12) = x3;
    } else {
        char* ost = smem;                // 16 rows * 528B bf16
        #pragma unroll
        for (int tt = 0; tt < 4; ++tt) {
            #pragma unroll
            for (int r = 0; r < 4; ++r)
                *reinterpret_cast<unsigned short*>(ost + (quad*4 + r)*528
                    + (w*64 + tt*16 + q16)*2) = f2bf(acc[tt][r] + bias[tt]);
        }
        __syncthreads();
        char* p = ost + (t >> 4)*528 + (t & 15)*32;
        uint4 a0 = *reinterpret_cast<uint4*>(p);
        uint4 a1 = *reinterpret_cast<uint4*>(p + 16);
        unsigned short* drow = (unsigned short*)out + (size_t)(tok0 + (t >> 4))*256 + (t & 15)*16;
        *reinterpret_cast<uint4*>(drow)     = a0;
        *reinterpret_cast<uint4*>(drow + 8) = a1;
    }
}

extern "C" void kernel_launch(void* const* d_in, const int* in_sizes, int n_in,
                              void* d_out, int out_size, void* d_ws, size_t ws_size,
                              hipStream_t stream)
{
    const void* x  = d_in[0];
    const void* Wq = d_in[1];
    const void* bq = d_in[2];
    const void* Wk = d_in[3];
    const void* bk = d_in[4];
    const void* Wv = d_in[5];
    const void* bv = d_in[6];
    const void* lw = d_in[7];
    const void* lb = d_in[8];
    const void* Wo = d_in[9];
    const void* bo = d_in[10];

    // ws: [flag 256B][q][k][v][o][lp][vT] bf16 | [D u8 5.3MB][scT 288KB]
    //     [xb bf16 2.36MB][Wt bf16 512KB][bb 5KB][lwT 25.6KB] | [pacc][pl]
    int* flag = (int*)d_ws;
    unsigned short* qb   = (unsigned short*)((char*)d_ws + 256);
    unsigned short* kbuf = qb   + (size_t)SZ;
    unsigned short* vbuf = kbuf + (size_t)SZ;
    unsigned short* obuf = vbuf + (size_t)SZ;
    unsigned short* lbuf = obuf + (size_t)SZ;
    unsigned short* vtb  = lbuf + (size_t)SZ;
    unsigned char*  Dtab = (unsigned char*)(vtb + (size_t)SZ);
    float2* scT = (float2*)(Dtab + (size_t)NN*NN);
    unsigned short* xb = (unsigned short*)(scT + (size_t)NN*16);
    unsigned short* Wt = xb + (size_t)SZ;
    float* bb  = (float*)(Wt + (size_t)4*256*256);
    float* lwT = bb + 5*256;

    const size_t base = 256 + 6*(size_t)SZ*2 + (size_t)NN*NN
                      + (size_t)NN*16*8 + (size_t)SZ*2
                      + (size_t)4*256*256*2 + (size_t)5*256*4 + (size_t)25*256*4;
    const size_t per_split = (size_t)16*NN*32*4 + (size_t)16*NN*4;  // pacc + pl
    int nsplit = 0;
    if      (ws_size >= base + 4*per_split) nsplit = 4;
    else if (ws_size >= base + 2*per_split) nsplit = 2;
    else if (ws_size >= base + 1*per_split) nsplit = 1;
    float* pacc = (float*)((char*)d_ws + base);
    float* pl   = pacc + (size_t)(nsplit ? nsplit : 1)*16*NN*32;

    prep_kernel<<<NN, 256, 0, stream>>>(x, Wq, bq, Wk, bk, Wv, bv, Wo, bo,
                                        lw, lb, flag, Dtab, scT, xb, Wt, bb, lwT);
    qkv_mfma<<<dim3(288,3), 256, 0, stream>>>(xb, Wt, bb, scT, qb, kbuf, vbuf, vtb);
    lepe_kernel<<<4608, 256, 0, stream>>>(vbuf, lwT, bb, lbuf);
    if (nsplit) {
        attn_kernel<0><<<dim3(16, 36, nsplit), 256, 0, stream>>>(qb, kbuf, vtb, Dtab, obuf, pacc, pl);
    } else {
        attn_kernel<1><<<dim3(16, 36, 1), 256, 0, stream>>>(qb, kbuf, vtb, Dtab, obuf, pacc, pl);
    }
    out_mfma<<<288, 256, 0, stream>>>(obuf, pacc, pl, lbuf, Wt, bb, flag, d_out, nsplit);
}